// Round 1
// baseline (184.917 us; speedup 1.0000x reference)
//
#include <hip/hip_runtime.h>

// BlockinnerAttention: b=1, h=8, T_q=2048, T=4096, dk=64, BS=64, top-2 blocks/query.
// fp32 in/out. One wave (64 lanes) per query; 4 waves per 256-thread block.

#define NH   8
#define TQ   2048
#define TKV  4096
#define DK   64
#define BSZ  64

__global__ __launch_bounds__(256) void blockattn_kernel(
    const float* __restrict__ q,
    const float* __restrict__ k,
    const float* __restrict__ v,
    const int*   __restrict__ top2,
    float*       __restrict__ out)
{
    const int wave = threadIdx.x >> 6;        // 0..3
    const int lane = threadIdx.x & 63;        // 0..63
    const int qidx = (blockIdx.x << 2) + wave; // 0..16383 (= bh*TQ + t)
    const int bh   = qidx >> 11;               // qidx / TQ  (TQ = 2048)

    __shared__ float q_sh[4][DK];
    __shared__ float p_sh[4][2 * BSZ];

    // top-2 block indices for this query
    const int2 idx = *(const int2*)(top2 + (size_t)qidx * 2);

    const size_t bh_off = (size_t)bh * (TKV * DK);
    const float* k0 = k + bh_off + (size_t)idx.x * (BSZ * DK) + lane * DK;
    const float* k1 = k + bh_off + (size_t)idx.y * (BSZ * DK) + lane * DK;

    // Stage q row into LDS (coalesced write; broadcast reads later)
    q_sh[wave][lane] = q[(size_t)qidx * DK + lane];
    __syncthreads();

    // ---- QK^T: lane j owns key row j of block0 and block1 ----
    float s0 = 0.f, s1 = 0.f;
#pragma unroll
    for (int c = 0; c < DK / 4; ++c) {
        const float4 a0 = *(const float4*)(k0 + c * 4);
        const float4 a1 = *(const float4*)(k1 + c * 4);
        const float4 qq = *(const float4*)(&q_sh[wave][c * 4]);
        s0 += a0.x * qq.x + a0.y * qq.y + a0.z * qq.z + a0.w * qq.w;
        s1 += a1.x * qq.x + a1.y * qq.y + a1.z * qq.z + a1.w * qq.w;
    }
    s0 *= 0.125f;  // 1/sqrt(64)
    s1 *= 0.125f;

    // ---- softmax over the 128 scores held across the wave (2/lane) ----
    float m = fmaxf(s0, s1);
#pragma unroll
    for (int off = 32; off > 0; off >>= 1) m = fmaxf(m, __shfl_xor(m, off));
    const float e0 = __expf(s0 - m);
    const float e1 = __expf(s1 - m);
    float sum = e0 + e1;
#pragma unroll
    for (int off = 32; off > 0; off >>= 1) sum += __shfl_xor(sum, off);
    const float inv = 1.0f / sum;

    p_sh[wave][lane]       = e0 * inv;
    p_sh[wave][BSZ + lane] = e1 * inv;
    __syncthreads();

    // ---- PV: lane d owns output dim d; V reads coalesced across lanes ----
    const float* v0 = v + bh_off + (size_t)idx.x * (BSZ * DK) + lane;
    const float* v1 = v + bh_off + (size_t)idx.y * (BSZ * DK) + lane;
    float acc = 0.f;
#pragma unroll 8
    for (int j = 0; j < BSZ; ++j) {
        acc += p_sh[wave][j]       * v0[(size_t)j * DK];
        acc += p_sh[wave][BSZ + j] * v1[(size_t)j * DK];
    }
    out[(size_t)qidx * DK + lane] = acc;
}

extern "C" void kernel_launch(void* const* d_in, const int* in_sizes, int n_in,
                              void* d_out, int out_size, void* d_ws, size_t ws_size,
                              hipStream_t stream) {
    const float* q    = (const float*)d_in[0];
    const float* k    = (const float*)d_in[1];
    const float* v    = (const float*)d_in[2];
    // d_in[3] is the scalar BS (=64), baked into the kernel constants.
    const int*   top2 = (const int*)d_in[4];
    float*       out  = (float*)d_out;

    const int n_queries = NH * TQ;            // 16384
    dim3 grid(n_queries / 4), block(256);     // 4 waves/block, 1 wave/query
    hipLaunchKernelGGL(blockattn_kernel, grid, block, 0, stream, q, k, v, top2, out);
}

// Round 2
// 112.061 us; speedup vs baseline: 1.6502x; 1.6502x over previous
//
#include <hip/hip_runtime.h>

// BlockinnerAttention: b=1, h=8, T_q=2048, T=4096, dk=64, BS=64, top-2 blocks/query.
// fp32 in/out. One wave per query. Fully-coalesced layout:
//   lane = (g = lane>>4, dc = lane&15); chunk i covers K/V rows 4i..4i+3,
//   lane loads row (4i+g), dims [4dc..4dc+3] -> wave load = contiguous 1 KB.
// Scores reduced within 16-lane groups (shfl_xor 1/2/4/8), softmax cross-group
// (shfl_xor 16/32). No LDS, no __syncthreads.

#define NH   8
#define TQ   2048
#define TKV  4096
#define DK   64
#define BSZ  64

__global__ __launch_bounds__(256) void blockattn_kernel(
    const float* __restrict__ q,
    const float* __restrict__ k,
    const float* __restrict__ v,
    const int*   __restrict__ top2,
    float*       __restrict__ out)
{
    const int wave = threadIdx.x >> 6;
    const int lane = threadIdx.x & 63;
    const int qidx = (blockIdx.x << 2) + wave;   // bh*TQ + t
    const int bh   = qidx >> 11;                 // / TQ
    const int g    = lane >> 4;                  // row-in-chunk group 0..3
    const int dc   = lane & 15;                  // dim chunk 0..15

    const int2 idx = *(const int2*)(top2 + (size_t)qidx * 2);
    const size_t bh_off = (size_t)bh * (TKV * DK);

    const int off = g * DK + dc * 4;             // lane offset within a 4-row chunk

    const float* kb0 = k + bh_off + (size_t)idx.x * (BSZ * DK) + off;
    const float* kb1 = k + bh_off + (size_t)idx.y * (BSZ * DK) + off;
    const float* vb0 = v + bh_off + (size_t)idx.x * (BSZ * DK) + off;
    const float* vb1 = v + bh_off + (size_t)idx.y * (BSZ * DK) + off;

    // q fragment for this lane's dim chunk (16 distinct float4s, broadcast x4)
    const float4 qf = *(const float4*)(q + (size_t)qidx * DK + dc * 4);

    // ---- QK^T: 32 coalesced 1 KB loads, group-reduced dots ----
    float sc[32];
#pragma unroll
    for (int i = 0; i < 16; ++i) {
        const float4 a = *(const float4*)(kb0 + i * 256);
        float p = a.x * qf.x + a.y * qf.y + a.z * qf.z + a.w * qf.w;
        p += __shfl_xor(p, 1);
        p += __shfl_xor(p, 2);
        p += __shfl_xor(p, 4);
        p += __shfl_xor(p, 8);
        sc[i] = p * 0.125f;                      // 1/sqrt(64)
    }
#pragma unroll
    for (int i = 0; i < 16; ++i) {
        const float4 a = *(const float4*)(kb1 + i * 256);
        float p = a.x * qf.x + a.y * qf.y + a.z * qf.z + a.w * qf.w;
        p += __shfl_xor(p, 1);
        p += __shfl_xor(p, 2);
        p += __shfl_xor(p, 4);
        p += __shfl_xor(p, 8);
        sc[16 + i] = p * 0.125f;
    }

    // ---- softmax: per-lane rows are distinct (row = 4i+g); groups replicate ----
    float m = sc[0];
#pragma unroll
    for (int i = 1; i < 32; ++i) m = fmaxf(m, sc[i]);
    m = fmaxf(m, __shfl_xor(m, 16));
    m = fmaxf(m, __shfl_xor(m, 32));

    float sum = 0.f;
#pragma unroll
    for (int i = 0; i < 32; ++i) {
        sc[i] = __expf(sc[i] - m);               // unnormalized weight
        sum += sc[i];
    }
    sum += __shfl_xor(sum, 16);
    sum += __shfl_xor(sum, 32);
    const float inv = 1.0f / sum;

    // ---- PV: same coalesced layout; weight rows, cross-group reduce ----
    float4 acc = make_float4(0.f, 0.f, 0.f, 0.f);
#pragma unroll
    for (int i = 0; i < 16; ++i) {
        const float4 a = *(const float4*)(vb0 + i * 256);
        const float w = sc[i];
        acc.x += a.x * w; acc.y += a.y * w; acc.z += a.z * w; acc.w += a.w * w;
    }
#pragma unroll
    for (int i = 0; i < 16; ++i) {
        const float4 a = *(const float4*)(vb1 + i * 256);
        const float w = sc[16 + i];
        acc.x += a.x * w; acc.y += a.y * w; acc.z += a.z * w; acc.w += a.w * w;
    }
    acc.x += __shfl_xor(acc.x, 16); acc.y += __shfl_xor(acc.y, 16);
    acc.z += __shfl_xor(acc.z, 16); acc.w += __shfl_xor(acc.w, 16);
    acc.x += __shfl_xor(acc.x, 32); acc.y += __shfl_xor(acc.y, 32);
    acc.z += __shfl_xor(acc.z, 32); acc.w += __shfl_xor(acc.w, 32);

    if (g == 0) {
        float4 o;
        o.x = acc.x * inv; o.y = acc.y * inv; o.z = acc.z * inv; o.w = acc.w * inv;
        *(float4*)(out + (size_t)qidx * DK + dc * 4) = o;
    }
}

extern "C" void kernel_launch(void* const* d_in, const int* in_sizes, int n_in,
                              void* d_out, int out_size, void* d_ws, size_t ws_size,
                              hipStream_t stream) {
    const float* q    = (const float*)d_in[0];
    const float* k    = (const float*)d_in[1];
    const float* v    = (const float*)d_in[2];
    // d_in[3] is the scalar BS (=64), baked into kernel constants.
    const int*   top2 = (const int*)d_in[4];
    float*       out  = (float*)d_out;

    const int n_queries = NH * TQ;            // 16384
    dim3 grid(n_queries / 4), block(256);     // 4 waves/block, 1 wave/query
    hipLaunchKernelGGL(blockattn_kernel, grid, block, 0, stream, q, k, v, top2, out);
}